// Round 4
// baseline (87.071 us; speedup 1.0000x reference)
//
#include <hip/hip_runtime.h>

// GFNet global filter: out = irfft2( rfft2(x) * W ), ortho norm, 14x14 spatial.
// x: (B=256, N=196, C=768) f32 ; W: (14, 8, C, 2) f32 ; out: (B, 196, C) f32.
//
// Dense small-DFT stages with compile-time twiddles, lane dim = channel.
// All stages use cos/sin symmetry pairing (j <-> 14-j); the h-FFT pair also
// uses radix-2 (14 = 2x7). Transposes run as re/im rounds through a single
// 28672 B LDS buffer -> 4 blocks/CU (32 waves, 100% wave ceiling).

static constexpr int CB     = 64;
static constexpr int NT     = 512;
static constexpr int CTILES = 768 / CB;   // 12

// cos/sin(2*pi*k/14)
static constexpr float C14[14] = {
     1.0f,
     0.90096886790241915f,  0.62348980185873359f,  0.22252093395631445f,
    -0.22252093395631434f, -0.62348980185873348f, -0.90096886790241915f,
    -1.0f,
    -0.90096886790241926f, -0.62348980185873371f, -0.22252093395631456f,
     0.22252093395631423f,  0.62348980185873337f,  0.90096886790241904f
};
static constexpr float S14[14] = {
     0.0f,
     0.43388373911755812f,  0.78183148246802980f,  0.97492791218182362f,
     0.97492791218182362f,  0.78183148246802991f,  0.43388373911755823f,
     0.0f,
    -0.43388373911755806f, -0.78183148246802958f, -0.97492791218182362f,
    -0.97492791218182373f, -0.78183148246802991f, -0.43388373911755834f
};

__global__ __launch_bounds__(NT, 8) void gfnet_filter(
    const float* __restrict__ x,
    const float* __restrict__ wgt,
    float* __restrict__ out)
{
    // 28672 B union buffer:
    //   G-re round: [h=0..13][u=0..7][64]        (28672 B)
    //   G-im round: [h=0..13][j=0..5][64]        (21504 B)  j = u-1, u=1..6
    //   P-re / P-im rounds: [m=0..13][v=0..7][64] (28672 B)
    __shared__ __align__(16) float LB[7168];

    const int bid = blockIdx.x;
    const int b   = bid / CTILES;
    const int ct  = bid - b * CTILES;
    const int c0  = ct * CB;
    const int tid = threadIdx.x;
    const int wv  = tid >> 6;
    const int ln  = tid & 63;
    // Row assignment for phases A/D: waves 5,6 (heavy complex-u columns in
    // B/C) get one row; all others two. Coverage: r0=0..7, r1={8,10,11,12,13,9}.
    const bool two = (wv <= 4) || (wv == 7);
    const int r0 = wv;
    const int r1 = (wv == 0) ? 8 : ((wv == 7) ? 9 : wv + 9);

    const float* xb = x + (size_t)b * 196 * 768 + c0 + ln;

    // ---------------- phase A: rfft along w (symmetry-paired) ----------------
    float A0r[8], A0i[7], A1r[8], A1i[7];   // i-index 1..6 used
    {
        float v0[14], v1[14];
        #pragma unroll
        for (int w = 0; w < 14; ++w) v0[w] = xb[(size_t)(r0 * 14 + w) * 768];
        if (two) {
            #pragma unroll
            for (int w = 0; w < 14; ++w) v1[w] = xb[(size_t)(r1 * 14 + w) * 768];
        }
        {
            float s[7], d[7];
            #pragma unroll
            for (int j = 1; j <= 6; ++j) { s[j] = v0[j] + v0[14 - j]; d[j] = v0[j] - v0[14 - j]; }
            A0r[0] = v0[0] + v0[7] + s[1] + s[2] + s[3] + s[4] + s[5] + s[6];
            A0r[7] = v0[0] - v0[7] - s[1] + s[2] - s[3] + s[4] - s[5] + s[6];
            #pragma unroll
            for (int u = 1; u <= 6; ++u) {
                float re = (u & 1) ? (v0[0] - v0[7]) : (v0[0] + v0[7]);
                float im = 0.f;
                #pragma unroll
                for (int j = 1; j <= 6; ++j) {
                    re = fmaf(s[j],  C14[(u * j) % 14], re);
                    im = fmaf(d[j], -S14[(u * j) % 14], im);
                }
                A0r[u] = re; A0i[u] = im;
            }
        }
        if (two) {
            float s[7], d[7];
            #pragma unroll
            for (int j = 1; j <= 6; ++j) { s[j] = v1[j] + v1[14 - j]; d[j] = v1[j] - v1[14 - j]; }
            A1r[0] = v1[0] + v1[7] + s[1] + s[2] + s[3] + s[4] + s[5] + s[6];
            A1r[7] = v1[0] - v1[7] - s[1] + s[2] - s[3] + s[4] - s[5] + s[6];
            #pragma unroll
            for (int u = 1; u <= 6; ++u) {
                float re = (u & 1) ? (v1[0] - v1[7]) : (v1[0] + v1[7]);
                float im = 0.f;
                #pragma unroll
                for (int j = 1; j <= 6; ++j) {
                    re = fmaf(s[j],  C14[(u * j) % 14], re);
                    im = fmaf(d[j], -S14[(u * j) % 14], im);
                }
                A1r[u] = re; A1i[u] = im;
            }
        }
    }

    // ---------------- G transpose, re round ----------------
    #pragma unroll
    for (int u = 0; u < 8; ++u) LB[(r0 * 8 + u) * 64 + ln] = A0r[u];
    if (two) {
        #pragma unroll
        for (int u = 0; u < 8; ++u) LB[(r1 * 8 + u) * 64 + ln] = A1r[u];
    }
    __syncthreads();                    // bar1: G-re visible
    float gr[14], gi[14];
    #pragma unroll
    for (int h = 0; h < 14; ++h) gr[h] = LB[(h * 8 + wv) * 64 + ln];
    __syncthreads();                    // bar2: G-re reads done

    // ---------------- G transpose, im round ----------------
    #pragma unroll
    for (int u = 1; u <= 6; ++u) LB[(r0 * 6 + (u - 1)) * 64 + ln] = A0i[u];
    if (two) {
        #pragma unroll
        for (int u = 1; u <= 6; ++u) LB[(r1 * 6 + (u - 1)) * 64 + ln] = A1i[u];
    }
    __syncthreads();                    // bar3: G-im visible
    if (wv >= 1 && wv <= 6) {
        #pragma unroll
        for (int h = 0; h < 14; ++h) gi[h] = LB[(h * 6 + (wv - 1)) * 64 + ln];
    } else {
        #pragma unroll
        for (int h = 0; h < 14; ++h) gi[h] = 0.f;
    }
    // (no barrier here: the read->overwrite hazard barrier sits after B/H/C,
    //  where all waves arrive together)

    // ---------------- phase B: a[k] = FFT_h(g), radix-2 + pairing ----------------
    float esr[3], esi[3], edr[3], edi[3], osr[3], osi[3], odr[3], odi[3];
    #pragma unroll
    for (int i = 0; i < 3; ++i) {
        int j = 2 * (i + 1);
        esr[i] = gr[j] + gr[14 - j]; esi[i] = gi[j] + gi[14 - j];
        edr[i] = gr[j] - gr[14 - j]; edi[i] = gi[j] - gi[14 - j];
        j = 2 * i + 1;
        osr[i] = gr[j] + gr[14 - j]; osi[i] = gi[j] + gi[14 - j];
        odr[i] = gr[j] - gr[14 - j]; odi[i] = gi[j] - gi[14 - j];
    }
    float Ekr[7], Eki[7], Okr[7], Oki[7];
    Ekr[0] = gr[0] + esr[0] + esr[1] + esr[2];
    Eki[0] = gi[0] + esi[0] + esi[1] + esi[2];
    Okr[0] = gr[7] + osr[0] + osr[1] + osr[2];
    Oki[0] = gi[7] + osi[0] + osi[1] + osi[2];
    #pragma unroll
    for (int k = 1; k <= 6; ++k) {
        float er = gr[0], ei = gi[0];
        #pragma unroll
        for (int i = 0; i < 3; ++i) {
            const int j = 2 * (i + 1);
            const float c = C14[(j * k) % 14], s2 = S14[(j * k) % 14];
            er = fmaf(esr[i], c, er); er = fmaf(edi[i],  s2, er);
            ei = fmaf(esi[i], c, ei); ei = fmaf(edr[i], -s2, ei);
        }
        Ekr[k] = er; Eki[k] = ei;
        float onr = (k & 1) ? -gr[7] : gr[7];
        float oni = (k & 1) ? -gi[7] : gi[7];
        #pragma unroll
        for (int i = 0; i < 3; ++i) {
            const int j = 2 * i + 1;
            const float c = C14[(j * k) % 14], s2 = S14[(j * k) % 14];
            onr = fmaf(osr[i], c, onr); onr = fmaf(odi[i],  s2, onr);
            oni = fmaf(osi[i], c, oni); oni = fmaf(odr[i], -s2, oni);
        }
        Okr[k] = onr; Oki[k] = oni;
    }

    // ---------------- weight multiply: H[k] = a[k] * w[k] ----------------
    float Hr[14], Hi[14];
    {
        const float2* wb = reinterpret_cast<const float2*>(wgt) + (size_t)wv * 768 + c0 + ln;
        #pragma unroll
        for (int k = 0; k < 7; ++k) {
            const float2 wA = wb[(size_t)k * (8 * 768)];
            const float2 wB = wb[(size_t)(k + 7) * (8 * 768)];
            const float ar = Ekr[k] + Okr[k], ai = Eki[k] + Oki[k];
            const float br = Ekr[k] - Okr[k], bi = Eki[k] - Oki[k];
            Hr[k]     = fmaf(ar, wA.x, -(ai * wA.y));
            Hi[k]     = fmaf(ar, wA.y,   ai * wA.x);
            Hr[k + 7] = fmaf(br, wB.x, -(bi * wB.y));
            Hi[k + 7] = fmaf(br, wB.y,   bi * wB.x);
        }
    }

    // ---------------- phase C: P = IFFT_h(H), radix-2 + pairing ----------------
    float qsr[3], qsi[3], qdr[3], qdi[3], rsr[3], rsi[3], rdr[3], rdi[3];
    #pragma unroll
    for (int i = 0; i < 3; ++i) {
        int j = 2 * (i + 1);
        qsr[i] = Hr[j] + Hr[14 - j]; qsi[i] = Hi[j] + Hi[14 - j];
        qdr[i] = Hr[j] - Hr[14 - j]; qdi[i] = Hi[j] - Hi[14 - j];
        j = 2 * i + 1;
        rsr[i] = Hr[j] + Hr[14 - j]; rsi[i] = Hi[j] + Hi[14 - j];
        rdr[i] = Hr[j] - Hr[14 - j]; rdi[i] = Hi[j] - Hi[14 - j];
    }
    float Qr[7], Qi[7], Rr[7], Ri[7];
    Qr[0] = Hr[0] + qsr[0] + qsr[1] + qsr[2];
    Qi[0] = Hi[0] + qsi[0] + qsi[1] + qsi[2];
    Rr[0] = Hr[7] + rsr[0] + rsr[1] + rsr[2];
    Ri[0] = Hi[7] + rsi[0] + rsi[1] + rsi[2];
    #pragma unroll
    for (int m = 1; m <= 6; ++m) {
        float qr = Hr[0], qi2 = Hi[0];
        #pragma unroll
        for (int i = 0; i < 3; ++i) {
            const int j = 2 * (i + 1);
            const float c = C14[(j * m) % 14], s2 = S14[(j * m) % 14];
            qr  = fmaf(qsr[i], c, qr);  qr  = fmaf(qdi[i], -s2, qr);
            qi2 = fmaf(qsi[i], c, qi2); qi2 = fmaf(qdr[i],  s2, qi2);
        }
        Qr[m] = qr; Qi[m] = qi2;
        float rr = (m & 1) ? -Hr[7] : Hr[7];
        float ri2 = (m & 1) ? -Hi[7] : Hi[7];
        #pragma unroll
        for (int i = 0; i < 3; ++i) {
            const int j = 2 * i + 1;
            const float c = C14[(j * m) % 14], s2 = S14[(j * m) % 14];
            rr  = fmaf(rsr[i], c, rr);  rr  = fmaf(rdi[i], -s2, rr);
            ri2 = fmaf(rsi[i], c, ri2); ri2 = fmaf(rdr[i],  s2, ri2);
        }
        Rr[m] = rr; Ri[m] = ri2;
    }

    __syncthreads();                    // bar4: all G-im reads done, buffer free

    // ---------------- P transpose (re round) + phase D t1 ----------------
    #pragma unroll
    for (int m = 0; m < 7; ++m) {
        LB[(m * 8 + wv) * 64 + ln]       = Qr[m] + Rr[m];
        LB[((m + 7) * 8 + wv) * 64 + ln] = Qr[m] - Rr[m];
    }
    __syncthreads();                    // bar5: P-re visible
    float t1a[8], t1b[8];
    {
        float a0[8], a1[8];
        #pragma unroll
        for (int v = 0; v < 8; ++v) {
            const float beta = (v == 0 || v == 7) ? (1.0f / 196.0f) : (2.0f / 196.0f);
            a0[v] = LB[(r0 * 8 + v) * 64 + ln] * beta;
            if (two) a1[v] = LB[(r1 * 8 + v) * 64 + ln] * beta;
        }
        t1a[0] = a0[0] + a0[7] + a0[1] + a0[2] + a0[3] + a0[4] + a0[5] + a0[6];
        t1a[7] = a0[0] - a0[7] - a0[1] + a0[2] - a0[3] + a0[4] - a0[5] + a0[6];
        #pragma unroll
        for (int wp = 1; wp <= 6; ++wp) {
            float t = (wp & 1) ? (a0[0] - a0[7]) : (a0[0] + a0[7]);
            #pragma unroll
            for (int v = 1; v <= 6; ++v) t = fmaf(a0[v], C14[(v * wp) % 14], t);
            t1a[wp] = t;
        }
        if (two) {
            t1b[0] = a1[0] + a1[7] + a1[1] + a1[2] + a1[3] + a1[4] + a1[5] + a1[6];
            t1b[7] = a1[0] - a1[7] - a1[1] + a1[2] - a1[3] + a1[4] - a1[5] + a1[6];
            #pragma unroll
            for (int wp = 1; wp <= 6; ++wp) {
                float t = (wp & 1) ? (a1[0] - a1[7]) : (a1[0] + a1[7]);
                #pragma unroll
                for (int v = 1; v <= 6; ++v) t = fmaf(a1[v], C14[(v * wp) % 14], t);
                t1b[wp] = t;
            }
        }
    }
    __syncthreads();                    // bar6: P-re reads done

    // ---------------- P transpose (im round) + phase D t2 + stores ----------------
    #pragma unroll
    for (int m = 0; m < 7; ++m) {
        LB[(m * 8 + wv) * 64 + ln]       = Qi[m] + Ri[m];
        LB[((m + 7) * 8 + wv) * 64 + ln] = Qi[m] - Ri[m];
    }
    __syncthreads();                    // bar7: P-im visible
    {
        float* ob = out + (size_t)b * 196 * 768 + c0 + ln;
        float b0[7], b1[7];
        #pragma unroll
        for (int v = 1; v <= 6; ++v) {
            b0[v] = LB[(r0 * 8 + v) * 64 + ln] * (2.0f / 196.0f);
            if (two) b1[v] = LB[(r1 * 8 + v) * 64 + ln] * (2.0f / 196.0f);
        }
        ob[(size_t)(r0 * 14 + 0) * 768] = t1a[0];
        ob[(size_t)(r0 * 14 + 7) * 768] = t1a[7];
        #pragma unroll
        for (int wp = 1; wp <= 6; ++wp) {
            float t = 0.f;
            #pragma unroll
            for (int v = 1; v <= 6; ++v) t = fmaf(b0[v], S14[(v * wp) % 14], t);
            ob[(size_t)(r0 * 14 + wp) * 768]      = t1a[wp] - t;
            ob[(size_t)(r0 * 14 + 14 - wp) * 768] = t1a[wp] + t;
        }
        if (two) {
            ob[(size_t)(r1 * 14 + 0) * 768] = t1b[0];
            ob[(size_t)(r1 * 14 + 7) * 768] = t1b[7];
            #pragma unroll
            for (int wp = 1; wp <= 6; ++wp) {
                float t = 0.f;
                #pragma unroll
                for (int v = 1; v <= 6; ++v) t = fmaf(b1[v], S14[(v * wp) % 14], t);
                ob[(size_t)(r1 * 14 + wp) * 768]      = t1b[wp] - t;
                ob[(size_t)(r1 * 14 + 14 - wp) * 768] = t1b[wp] + t;
            }
        }
    }
}

extern "C" void kernel_launch(void* const* d_in, const int* in_sizes, int n_in,
                              void* d_out, int out_size, void* d_ws, size_t ws_size,
                              hipStream_t stream) {
    const float* x   = (const float*)d_in[0];
    const float* wgt = (const float*)d_in[1];
    float*       o   = (float*)d_out;

    const int B = in_sizes[0] / (196 * 768);   // 256
    dim3 grid(B * CTILES), block(NT);
    gfnet_filter<<<grid, block, 0, stream>>>(x, wgt, o);
}

// Round 5
// 82.258 us; speedup vs baseline: 1.0585x; 1.0585x over previous
//
#include <hip/hip_runtime.h>

// GFNet global filter: out = irfft2( rfft2(x) * W ), ortho norm, 14x14 spatial.
// x: (B=256, N=196, C=768) f32 ; W: (14, 8, C, 2) f32 ; out: (B, 196, C) f32.
//
// Dense small-DFT stages with compile-time twiddles, lane dim = channel.
// All stages use cos/sin symmetry pairing (j <-> 14-j); the h-FFT pair also
// uses radix-2 (14 = 2x7). Transposes run as re/im rounds through a single
// 28672 B LDS buffer -> 4 blocks/CU possible.
// launch_bounds(512,6): R4's (512,8) forced VGPR 32 -> scratch spills
// (+84 MB HBM traffic/dispatch). (512,6) lets the allocator sit at ~40-48
// VGPR (<=64 keeps 8 waves/EU), no spill.

static constexpr int CB     = 64;
static constexpr int NT     = 512;
static constexpr int CTILES = 768 / CB;   // 12

// cos/sin(2*pi*k/14)
static constexpr float C14[14] = {
     1.0f,
     0.90096886790241915f,  0.62348980185873359f,  0.22252093395631445f,
    -0.22252093395631434f, -0.62348980185873348f, -0.90096886790241915f,
    -1.0f,
    -0.90096886790241926f, -0.62348980185873371f, -0.22252093395631456f,
     0.22252093395631423f,  0.62348980185873337f,  0.90096886790241904f
};
static constexpr float S14[14] = {
     0.0f,
     0.43388373911755812f,  0.78183148246802980f,  0.97492791218182362f,
     0.97492791218182362f,  0.78183148246802991f,  0.43388373911755823f,
     0.0f,
    -0.43388373911755806f, -0.78183148246802958f, -0.97492791218182362f,
    -0.97492791218182373f, -0.78183148246802991f, -0.43388373911755834f
};

__global__ __launch_bounds__(NT, 6) void gfnet_filter(
    const float* __restrict__ x,
    const float* __restrict__ wgt,
    float* __restrict__ out)
{
    // 28672 B union buffer:
    //   G-re round: [h=0..13][u=0..7][64]        (28672 B)
    //   G-im round: [h=0..13][j=0..5][64]        (21504 B)  j = u-1, u=1..6
    //   P-re / P-im rounds: [m=0..13][v=0..7][64] (28672 B)
    __shared__ __align__(16) float LB[7168];

    const int bid = blockIdx.x;
    const int b   = bid / CTILES;
    const int ct  = bid - b * CTILES;
    const int c0  = ct * CB;
    const int tid = threadIdx.x;
    const int wv  = tid >> 6;
    const int ln  = tid & 63;
    // Row assignment for phases A/D: waves 5,6 (heavy complex-u columns in
    // B/C) get one row; all others two. Coverage: r0=0..7, r1={8,10,11,12,13,9}.
    const bool two = (wv <= 4) || (wv == 7);
    const int r0 = wv;
    const int r1 = (wv == 0) ? 8 : ((wv == 7) ? 9 : wv + 9);

    const float* xb = x + (size_t)b * 196 * 768 + c0 + ln;

    // ---------------- phase A: rfft along w (symmetry-paired) ----------------
    float A0r[8], A0i[7], A1r[8], A1i[7];   // i-index 1..6 used
    {
        float v0[14], v1[14];
        #pragma unroll
        for (int w = 0; w < 14; ++w) v0[w] = xb[(size_t)(r0 * 14 + w) * 768];
        if (two) {
            #pragma unroll
            for (int w = 0; w < 14; ++w) v1[w] = xb[(size_t)(r1 * 14 + w) * 768];
        }
        {
            float s[7], d[7];
            #pragma unroll
            for (int j = 1; j <= 6; ++j) { s[j] = v0[j] + v0[14 - j]; d[j] = v0[j] - v0[14 - j]; }
            A0r[0] = v0[0] + v0[7] + s[1] + s[2] + s[3] + s[4] + s[5] + s[6];
            A0r[7] = v0[0] - v0[7] - s[1] + s[2] - s[3] + s[4] - s[5] + s[6];
            #pragma unroll
            for (int u = 1; u <= 6; ++u) {
                float re = (u & 1) ? (v0[0] - v0[7]) : (v0[0] + v0[7]);
                float im = 0.f;
                #pragma unroll
                for (int j = 1; j <= 6; ++j) {
                    re = fmaf(s[j],  C14[(u * j) % 14], re);
                    im = fmaf(d[j], -S14[(u * j) % 14], im);
                }
                A0r[u] = re; A0i[u] = im;
            }
        }
        if (two) {
            float s[7], d[7];
            #pragma unroll
            for (int j = 1; j <= 6; ++j) { s[j] = v1[j] + v1[14 - j]; d[j] = v1[j] - v1[14 - j]; }
            A1r[0] = v1[0] + v1[7] + s[1] + s[2] + s[3] + s[4] + s[5] + s[6];
            A1r[7] = v1[0] - v1[7] - s[1] + s[2] - s[3] + s[4] - s[5] + s[6];
            #pragma unroll
            for (int u = 1; u <= 6; ++u) {
                float re = (u & 1) ? (v1[0] - v1[7]) : (v1[0] + v1[7]);
                float im = 0.f;
                #pragma unroll
                for (int j = 1; j <= 6; ++j) {
                    re = fmaf(s[j],  C14[(u * j) % 14], re);
                    im = fmaf(d[j], -S14[(u * j) % 14], im);
                }
                A1r[u] = re; A1i[u] = im;
            }
        }
    }

    // ---------------- G transpose, re round ----------------
    #pragma unroll
    for (int u = 0; u < 8; ++u) LB[(r0 * 8 + u) * 64 + ln] = A0r[u];
    if (two) {
        #pragma unroll
        for (int u = 0; u < 8; ++u) LB[(r1 * 8 + u) * 64 + ln] = A1r[u];
    }
    __syncthreads();                    // bar1: G-re visible
    float gr[14], gi[14];
    #pragma unroll
    for (int h = 0; h < 14; ++h) gr[h] = LB[(h * 8 + wv) * 64 + ln];
    __syncthreads();                    // bar2: G-re reads done

    // ---------------- G transpose, im round ----------------
    #pragma unroll
    for (int u = 1; u <= 6; ++u) LB[(r0 * 6 + (u - 1)) * 64 + ln] = A0i[u];
    if (two) {
        #pragma unroll
        for (int u = 1; u <= 6; ++u) LB[(r1 * 6 + (u - 1)) * 64 + ln] = A1i[u];
    }
    __syncthreads();                    // bar3: G-im visible
    if (wv >= 1 && wv <= 6) {
        #pragma unroll
        for (int h = 0; h < 14; ++h) gi[h] = LB[(h * 6 + (wv - 1)) * 64 + ln];
    } else {
        #pragma unroll
        for (int h = 0; h < 14; ++h) gi[h] = 0.f;
    }
    // (no barrier here: the read->overwrite hazard barrier sits after B/H/C,
    //  where all waves arrive together)

    // ---------------- phase B: a[k] = FFT_h(g), radix-2 + pairing ----------------
    float esr[3], esi[3], edr[3], edi[3], osr[3], osi[3], odr[3], odi[3];
    #pragma unroll
    for (int i = 0; i < 3; ++i) {
        int j = 2 * (i + 1);
        esr[i] = gr[j] + gr[14 - j]; esi[i] = gi[j] + gi[14 - j];
        edr[i] = gr[j] - gr[14 - j]; edi[i] = gi[j] - gi[14 - j];
        j = 2 * i + 1;
        osr[i] = gr[j] + gr[14 - j]; osi[i] = gi[j] + gi[14 - j];
        odr[i] = gr[j] - gr[14 - j]; odi[i] = gi[j] - gi[14 - j];
    }
    float Ekr[7], Eki[7], Okr[7], Oki[7];
    Ekr[0] = gr[0] + esr[0] + esr[1] + esr[2];
    Eki[0] = gi[0] + esi[0] + esi[1] + esi[2];
    Okr[0] = gr[7] + osr[0] + osr[1] + osr[2];
    Oki[0] = gi[7] + osi[0] + osi[1] + osi[2];
    #pragma unroll
    for (int k = 1; k <= 6; ++k) {
        float er = gr[0], ei = gi[0];
        #pragma unroll
        for (int i = 0; i < 3; ++i) {
            const int j = 2 * (i + 1);
            const float c = C14[(j * k) % 14], s2 = S14[(j * k) % 14];
            er = fmaf(esr[i], c, er); er = fmaf(edi[i],  s2, er);
            ei = fmaf(esi[i], c, ei); ei = fmaf(edr[i], -s2, ei);
        }
        Ekr[k] = er; Eki[k] = ei;
        float onr = (k & 1) ? -gr[7] : gr[7];
        float oni = (k & 1) ? -gi[7] : gi[7];
        #pragma unroll
        for (int i = 0; i < 3; ++i) {
            const int j = 2 * i + 1;
            const float c = C14[(j * k) % 14], s2 = S14[(j * k) % 14];
            onr = fmaf(osr[i], c, onr); onr = fmaf(odi[i],  s2, onr);
            oni = fmaf(osi[i], c, oni); oni = fmaf(odr[i], -s2, oni);
        }
        Okr[k] = onr; Oki[k] = oni;
    }

    // ---------------- weight multiply: H[k] = a[k] * w[k] ----------------
    float Hr[14], Hi[14];
    {
        const float2* wb = reinterpret_cast<const float2*>(wgt) + (size_t)wv * 768 + c0 + ln;
        #pragma unroll
        for (int k = 0; k < 7; ++k) {
            const float2 wA = wb[(size_t)k * (8 * 768)];
            const float2 wB = wb[(size_t)(k + 7) * (8 * 768)];
            const float ar = Ekr[k] + Okr[k], ai = Eki[k] + Oki[k];
            const float br = Ekr[k] - Okr[k], bi = Eki[k] - Oki[k];
            Hr[k]     = fmaf(ar, wA.x, -(ai * wA.y));
            Hi[k]     = fmaf(ar, wA.y,   ai * wA.x);
            Hr[k + 7] = fmaf(br, wB.x, -(bi * wB.y));
            Hi[k + 7] = fmaf(br, wB.y,   bi * wB.x);
        }
    }

    // ---------------- phase C: P = IFFT_h(H), radix-2 + pairing ----------------
    float qsr[3], qsi[3], qdr[3], qdi[3], rsr[3], rsi[3], rdr[3], rdi[3];
    #pragma unroll
    for (int i = 0; i < 3; ++i) {
        int j = 2 * (i + 1);
        qsr[i] = Hr[j] + Hr[14 - j]; qsi[i] = Hi[j] + Hi[14 - j];
        qdr[i] = Hr[j] - Hr[14 - j]; qdi[i] = Hi[j] - Hi[14 - j];
        j = 2 * i + 1;
        rsr[i] = Hr[j] + Hr[14 - j]; rsi[i] = Hi[j] + Hi[14 - j];
        rdr[i] = Hr[j] - Hr[14 - j]; rdi[i] = Hi[j] - Hi[14 - j];
    }
    float Qr[7], Qi[7], Rr[7], Ri[7];
    Qr[0] = Hr[0] + qsr[0] + qsr[1] + qsr[2];
    Qi[0] = Hi[0] + qsi[0] + qsi[1] + qsi[2];
    Rr[0] = Hr[7] + rsr[0] + rsr[1] + rsr[2];
    Ri[0] = Hi[7] + rsi[0] + rsi[1] + rsi[2];
    #pragma unroll
    for (int m = 1; m <= 6; ++m) {
        float qr = Hr[0], qi2 = Hi[0];
        #pragma unroll
        for (int i = 0; i < 3; ++i) {
            const int j = 2 * (i + 1);
            const float c = C14[(j * m) % 14], s2 = S14[(j * m) % 14];
            qr  = fmaf(qsr[i], c, qr);  qr  = fmaf(qdi[i], -s2, qr);
            qi2 = fmaf(qsi[i], c, qi2); qi2 = fmaf(qdr[i],  s2, qi2);
        }
        Qr[m] = qr; Qi[m] = qi2;
        float rr = (m & 1) ? -Hr[7] : Hr[7];
        float ri2 = (m & 1) ? -Hi[7] : Hi[7];
        #pragma unroll
        for (int i = 0; i < 3; ++i) {
            const int j = 2 * i + 1;
            const float c = C14[(j * m) % 14], s2 = S14[(j * m) % 14];
            rr  = fmaf(rsr[i], c, rr);  rr  = fmaf(rdi[i], -s2, rr);
            ri2 = fmaf(rsi[i], c, ri2); ri2 = fmaf(rdr[i],  s2, ri2);
        }
        Rr[m] = rr; Ri[m] = ri2;
    }

    __syncthreads();                    // bar4: all G-im reads done, buffer free

    // ---------------- P transpose (re round) + phase D t1 ----------------
    #pragma unroll
    for (int m = 0; m < 7; ++m) {
        LB[(m * 8 + wv) * 64 + ln]       = Qr[m] + Rr[m];
        LB[((m + 7) * 8 + wv) * 64 + ln] = Qr[m] - Rr[m];
    }
    __syncthreads();                    // bar5: P-re visible
    float t1a[8], t1b[8];
    {
        float a0[8], a1[8];
        #pragma unroll
        for (int v = 0; v < 8; ++v) {
            const float beta = (v == 0 || v == 7) ? (1.0f / 196.0f) : (2.0f / 196.0f);
            a0[v] = LB[(r0 * 8 + v) * 64 + ln] * beta;
            if (two) a1[v] = LB[(r1 * 8 + v) * 64 + ln] * beta;
        }
        t1a[0] = a0[0] + a0[7] + a0[1] + a0[2] + a0[3] + a0[4] + a0[5] + a0[6];
        t1a[7] = a0[0] - a0[7] - a0[1] + a0[2] - a0[3] + a0[4] - a0[5] + a0[6];
        #pragma unroll
        for (int wp = 1; wp <= 6; ++wp) {
            float t = (wp & 1) ? (a0[0] - a0[7]) : (a0[0] + a0[7]);
            #pragma unroll
            for (int v = 1; v <= 6; ++v) t = fmaf(a0[v], C14[(v * wp) % 14], t);
            t1a[wp] = t;
        }
        if (two) {
            t1b[0] = a1[0] + a1[7] + a1[1] + a1[2] + a1[3] + a1[4] + a1[5] + a1[6];
            t1b[7] = a1[0] - a1[7] - a1[1] + a1[2] - a1[3] + a1[4] - a1[5] + a1[6];
            #pragma unroll
            for (int wp = 1; wp <= 6; ++wp) {
                float t = (wp & 1) ? (a1[0] - a1[7]) : (a1[0] + a1[7]);
                #pragma unroll
                for (int v = 1; v <= 6; ++v) t = fmaf(a1[v], C14[(v * wp) % 14], t);
                t1b[wp] = t;
            }
        }
    }
    __syncthreads();                    // bar6: P-re reads done

    // ---------------- P transpose (im round) + phase D t2 + stores ----------------
    #pragma unroll
    for (int m = 0; m < 7; ++m) {
        LB[(m * 8 + wv) * 64 + ln]       = Qi[m] + Ri[m];
        LB[((m + 7) * 8 + wv) * 64 + ln] = Qi[m] - Ri[m];
    }
    __syncthreads();                    // bar7: P-im visible
    {
        float* ob = out + (size_t)b * 196 * 768 + c0 + ln;
        float b0[7], b1[7];
        #pragma unroll
        for (int v = 1; v <= 6; ++v) {
            b0[v] = LB[(r0 * 8 + v) * 64 + ln] * (2.0f / 196.0f);
            if (two) b1[v] = LB[(r1 * 8 + v) * 64 + ln] * (2.0f / 196.0f);
        }
        ob[(size_t)(r0 * 14 + 0) * 768] = t1a[0];
        ob[(size_t)(r0 * 14 + 7) * 768] = t1a[7];
        #pragma unroll
        for (int wp = 1; wp <= 6; ++wp) {
            float t = 0.f;
            #pragma unroll
            for (int v = 1; v <= 6; ++v) t = fmaf(b0[v], S14[(v * wp) % 14], t);
            ob[(size_t)(r0 * 14 + wp) * 768]      = t1a[wp] - t;
            ob[(size_t)(r0 * 14 + 14 - wp) * 768] = t1a[wp] + t;
        }
        if (two) {
            ob[(size_t)(r1 * 14 + 0) * 768] = t1b[0];
            ob[(size_t)(r1 * 14 + 7) * 768] = t1b[7];
            #pragma unroll
            for (int wp = 1; wp <= 6; ++wp) {
                float t = 0.f;
                #pragma unroll
                for (int v = 1; v <= 6; ++v) t = fmaf(b1[v], S14[(v * wp) % 14], t);
                ob[(size_t)(r1 * 14 + wp) * 768]      = t1b[wp] - t;
                ob[(size_t)(r1 * 14 + 14 - wp) * 768] = t1b[wp] + t;
            }
        }
    }
}

extern "C" void kernel_launch(void* const* d_in, const int* in_sizes, int n_in,
                              void* d_out, int out_size, void* d_ws, size_t ws_size,
                              hipStream_t stream) {
    const float* x   = (const float*)d_in[0];
    const float* wgt = (const float*)d_in[1];
    float*       o   = (float*)d_out;

    const int B = in_sizes[0] / (196 * 768);   // 256
    dim3 grid(B * CTILES), block(NT);
    gfnet_filter<<<grid, block, 0, stream>>>(x, wgt, o);
}

// Round 6
// 74.366 us; speedup vs baseline: 1.1708x; 1.1061x over previous
//
#include <hip/hip_runtime.h>

// GFNet global filter: out = irfft2( rfft2(x) * W ), ortho norm, 14x14 spatial.
// x: (B=256, N=196, C=768) f32 ; W: (14, 8, C, 2) f32 ; out: (B, 196, C) f32.
//
// Dense small-DFT stages with compile-time twiddles, lane dim = channel.
// All stages use cos/sin symmetry pairing (j <-> 14-j); the h-FFT pair also
// uses radix-2 (14 = 2x7). Transposes split by h-halves with complex pairs
// kept together (float2), through one 28672 B LDS buffer.
//
// NOTE on __launch_bounds__: measured on this toolchain, the 2nd arg acts as
// CUDA-style MIN BLOCKS PER CU: (512,8) gave VGPR=32 (=512/16 waves/EU) and
// (512,6) gave VGPR=40 (~512/12) -> both spilled (WRITE_SIZE exceeded output
// bytes). (512,3) budgets >=85 VGPR -> no spill; it's only a minimum, so
// VGPR<=64 still yields 4 blocks/CU at 28672 B LDS.

static constexpr int CB     = 64;
static constexpr int NT     = 512;
static constexpr int CTILES = 768 / CB;   // 12

// cos/sin(2*pi*k/14)
static constexpr float C14[14] = {
     1.0f,
     0.90096886790241915f,  0.62348980185873359f,  0.22252093395631445f,
    -0.22252093395631434f, -0.62348980185873348f, -0.90096886790241915f,
    -1.0f,
    -0.90096886790241926f, -0.62348980185873371f, -0.22252093395631456f,
     0.22252093395631423f,  0.62348980185873337f,  0.90096886790241904f
};
static constexpr float S14[14] = {
     0.0f,
     0.43388373911755812f,  0.78183148246802980f,  0.97492791218182362f,
     0.97492791218182362f,  0.78183148246802991f,  0.43388373911755823f,
     0.0f,
    -0.43388373911755806f, -0.78183148246802958f, -0.97492791218182362f,
    -0.97492791218182373f, -0.78183148246802991f, -0.43388373911755834f
};

__global__ __launch_bounds__(NT, 3) void gfnet_filter(
    const float* __restrict__ x,
    const float* __restrict__ wgt,
    float* __restrict__ out)
{
    // 28672 B buffer: 7 rows x 8 freq x 64 lanes, complex.
    //   G rounds: slot hh <-> row hh (round 1) / row hh+7 (round 2)
    //   P rounds: slot m  <-> row m (Q+R)      / row m+7 (Q-R)
    __shared__ __align__(16) float2 T[7 * 8 * 64];

    const int bid = blockIdx.x;
    const int b   = bid / CTILES;
    const int ct  = bid - b * CTILES;
    const int c0  = ct * CB;
    const int tid = threadIdx.x;
    const int wv  = tid >> 6;
    const int ln  = tid & 63;
    const bool two = (wv < 6);
    const int r0 = wv;          // rows handled in phases A/D
    const int r1 = wv + 8;

    const float* xb = x + (size_t)b * 196 * 768 + c0 + ln;

    // ---------------- phase A: rfft along w (symmetry-paired) ----------------
    float A0r[8], A0i[7], A1r[8], A1i[7];   // i-index 1..6 used
    {
        float v0[14], v1[14];
        #pragma unroll
        for (int w = 0; w < 14; ++w) v0[w] = xb[(size_t)(r0 * 14 + w) * 768];
        if (two) {
            #pragma unroll
            for (int w = 0; w < 14; ++w) v1[w] = xb[(size_t)(r1 * 14 + w) * 768];
        }
        {
            float s[7], d[7];
            #pragma unroll
            for (int j = 1; j <= 6; ++j) { s[j] = v0[j] + v0[14 - j]; d[j] = v0[j] - v0[14 - j]; }
            A0r[0] = v0[0] + v0[7] + s[1] + s[2] + s[3] + s[4] + s[5] + s[6];
            A0r[7] = v0[0] - v0[7] - s[1] + s[2] - s[3] + s[4] - s[5] + s[6];
            #pragma unroll
            for (int u = 1; u <= 6; ++u) {
                float re = (u & 1) ? (v0[0] - v0[7]) : (v0[0] + v0[7]);
                float im = 0.f;
                #pragma unroll
                for (int j = 1; j <= 6; ++j) {
                    re = fmaf(s[j],  C14[(u * j) % 14], re);
                    im = fmaf(d[j], -S14[(u * j) % 14], im);
                }
                A0r[u] = re; A0i[u] = im;
            }
        }
        if (two) {
            float s[7], d[7];
            #pragma unroll
            for (int j = 1; j <= 6; ++j) { s[j] = v1[j] + v1[14 - j]; d[j] = v1[j] - v1[14 - j]; }
            A1r[0] = v1[0] + v1[7] + s[1] + s[2] + s[3] + s[4] + s[5] + s[6];
            A1r[7] = v1[0] - v1[7] - s[1] + s[2] - s[3] + s[4] - s[5] + s[6];
            #pragma unroll
            for (int u = 1; u <= 6; ++u) {
                float re = (u & 1) ? (v1[0] - v1[7]) : (v1[0] + v1[7]);
                float im = 0.f;
                #pragma unroll
                for (int j = 1; j <= 6; ++j) {
                    re = fmaf(s[j],  C14[(u * j) % 14], re);
                    im = fmaf(d[j], -S14[(u * j) % 14], im);
                }
                A1r[u] = re; A1i[u] = im;
            }
        }
    }

    // ---------------- G transpose, round 1: rows 0..6 ----------------
    if (wv < 7) {
        #pragma unroll
        for (int u = 0; u < 8; ++u)
            T[(r0 * 8 + u) * 64 + ln] =
                make_float2(A0r[u], (u >= 1 && u <= 6) ? A0i[u] : 0.f);
    }
    __syncthreads();                    // bar1: rows 0..6 visible
    float gr[14], gi[14];
    #pragma unroll
    for (int hh = 0; hh < 7; ++hh) {
        float2 t = T[(hh * 8 + wv) * 64 + ln];
        gr[hh] = t.x; gi[hh] = t.y;
    }
    __syncthreads();                    // bar2: round-1 reads done

    // ---------------- G transpose, round 2: rows 7..13 ----------------
    if (wv == 7) {
        #pragma unroll
        for (int u = 0; u < 8; ++u)
            T[(0 * 8 + u) * 64 + ln] =
                make_float2(A0r[u], (u >= 1 && u <= 6) ? A0i[u] : 0.f);
    }
    if (two) {
        #pragma unroll
        for (int u = 0; u < 8; ++u)
            T[((wv + 1) * 8 + u) * 64 + ln] =
                make_float2(A1r[u], (u >= 1 && u <= 6) ? A1i[u] : 0.f);
    }
    __syncthreads();                    // bar3: rows 7..13 visible
    #pragma unroll
    for (int hh = 0; hh < 7; ++hh) {
        float2 t = T[(hh * 8 + wv) * 64 + ln];
        gr[hh + 7] = t.x; gi[hh + 7] = t.y;
    }
    // (read->overwrite hazard barrier deferred to after B/H/C, where all
    //  waves arrive together)

    // ---------------- phase B: a[k] = FFT_h(g), radix-2 + pairing ----------------
    float esr[3], esi[3], edr[3], edi[3], osr[3], osi[3], odr[3], odi[3];
    #pragma unroll
    for (int i = 0; i < 3; ++i) {
        int j = 2 * (i + 1);
        esr[i] = gr[j] + gr[14 - j]; esi[i] = gi[j] + gi[14 - j];
        edr[i] = gr[j] - gr[14 - j]; edi[i] = gi[j] - gi[14 - j];
        j = 2 * i + 1;
        osr[i] = gr[j] + gr[14 - j]; osi[i] = gi[j] + gi[14 - j];
        odr[i] = gr[j] - gr[14 - j]; odi[i] = gi[j] - gi[14 - j];
    }
    float Ekr[7], Eki[7], Okr[7], Oki[7];
    Ekr[0] = gr[0] + esr[0] + esr[1] + esr[2];
    Eki[0] = gi[0] + esi[0] + esi[1] + esi[2];
    Okr[0] = gr[7] + osr[0] + osr[1] + osr[2];
    Oki[0] = gi[7] + osi[0] + osi[1] + osi[2];
    #pragma unroll
    for (int k = 1; k <= 6; ++k) {
        float er = gr[0], ei = gi[0];
        #pragma unroll
        for (int i = 0; i < 3; ++i) {
            const int j = 2 * (i + 1);
            const float c = C14[(j * k) % 14], s2 = S14[(j * k) % 14];
            er = fmaf(esr[i], c, er); er = fmaf(edi[i],  s2, er);
            ei = fmaf(esi[i], c, ei); ei = fmaf(edr[i], -s2, ei);
        }
        Ekr[k] = er; Eki[k] = ei;
        float onr = (k & 1) ? -gr[7] : gr[7];
        float oni = (k & 1) ? -gi[7] : gi[7];
        #pragma unroll
        for (int i = 0; i < 3; ++i) {
            const int j = 2 * i + 1;
            const float c = C14[(j * k) % 14], s2 = S14[(j * k) % 14];
            onr = fmaf(osr[i], c, onr); onr = fmaf(odi[i],  s2, onr);
            oni = fmaf(osi[i], c, oni); oni = fmaf(odr[i], -s2, oni);
        }
        Okr[k] = onr; Oki[k] = oni;
    }

    // ---------------- weight multiply: H[k] = a[k] * w[k] ----------------
    float Hr[14], Hi[14];
    {
        const float2* wb = reinterpret_cast<const float2*>(wgt) + (size_t)wv * 768 + c0 + ln;
        #pragma unroll
        for (int k = 0; k < 7; ++k) {
            const float2 wA = wb[(size_t)k * (8 * 768)];
            const float2 wB = wb[(size_t)(k + 7) * (8 * 768)];
            const float ar = Ekr[k] + Okr[k], ai = Eki[k] + Oki[k];
            const float br = Ekr[k] - Okr[k], bi = Eki[k] - Oki[k];
            Hr[k]     = fmaf(ar, wA.x, -(ai * wA.y));
            Hi[k]     = fmaf(ar, wA.y,   ai * wA.x);
            Hr[k + 7] = fmaf(br, wB.x, -(bi * wB.y));
            Hi[k + 7] = fmaf(br, wB.y,   bi * wB.x);
        }
    }

    // ---------------- phase C: P = IFFT_h(H), radix-2 + pairing ----------------
    float qsr[3], qsi[3], qdr[3], qdi[3], rsr[3], rsi[3], rdr[3], rdi[3];
    #pragma unroll
    for (int i = 0; i < 3; ++i) {
        int j = 2 * (i + 1);
        qsr[i] = Hr[j] + Hr[14 - j]; qsi[i] = Hi[j] + Hi[14 - j];
        qdr[i] = Hr[j] - Hr[14 - j]; qdi[i] = Hi[j] - Hi[14 - j];
        j = 2 * i + 1;
        rsr[i] = Hr[j] + Hr[14 - j]; rsi[i] = Hi[j] + Hi[14 - j];
        rdr[i] = Hr[j] - Hr[14 - j]; rdi[i] = Hi[j] - Hi[14 - j];
    }
    float Qr[7], Qi[7], Rr[7], Ri[7];
    Qr[0] = Hr[0] + qsr[0] + qsr[1] + qsr[2];
    Qi[0] = Hi[0] + qsi[0] + qsi[1] + qsi[2];
    Rr[0] = Hr[7] + rsr[0] + rsr[1] + rsr[2];
    Ri[0] = Hi[7] + rsi[0] + rsi[1] + rsi[2];
    #pragma unroll
    for (int m = 1; m <= 6; ++m) {
        float qr = Hr[0], qi2 = Hi[0];
        #pragma unroll
        for (int i = 0; i < 3; ++i) {
            const int j = 2 * (i + 1);
            const float c = C14[(j * m) % 14], s2 = S14[(j * m) % 14];
            qr  = fmaf(qsr[i], c, qr);  qr  = fmaf(qdi[i], -s2, qr);
            qi2 = fmaf(qsi[i], c, qi2); qi2 = fmaf(qdr[i],  s2, qi2);
        }
        Qr[m] = qr; Qi[m] = qi2;
        float rr = (m & 1) ? -Hr[7] : Hr[7];
        float ri2 = (m & 1) ? -Hi[7] : Hi[7];
        #pragma unroll
        for (int i = 0; i < 3; ++i) {
            const int j = 2 * i + 1;
            const float c = C14[(j * m) % 14], s2 = S14[(j * m) % 14];
            rr  = fmaf(rsr[i], c, rr);  rr  = fmaf(rdi[i], -s2, rr);
            ri2 = fmaf(rsi[i], c, ri2); ri2 = fmaf(rdr[i],  s2, ri2);
        }
        Rr[m] = rr; Ri[m] = ri2;
    }

    __syncthreads();                    // bar4: all G reads done, buffer free

    float* ob = out + (size_t)b * 196 * 768 + c0 + ln;

    // ---------------- P round 1: rows 0..6 = Q+R; then kill R ----------------
    #pragma unroll
    for (int m = 0; m < 7; ++m)
        T[(m * 8 + wv) * 64 + ln] = make_float2(Qr[m] + Rr[m], Qi[m] + Ri[m]);
    #pragma unroll
    for (int m = 0; m < 7; ++m) { Qr[m] -= Rr[m]; Qi[m] -= Ri[m]; }   // now Q = Q-R
    __syncthreads();                    // bar5: P rows 0..6 visible
    if (wv < 7) {
        // full phase D for row r0 (= wv), slot wv
        float a0[8], b0v[7];
        #pragma unroll
        for (int v = 0; v < 8; ++v) {
            float2 t = T[(wv * 8 + v) * 64 + ln];
            a0[v] = t.x * ((v == 0 || v == 7) ? (1.0f / 196.0f) : (2.0f / 196.0f));
            if (v >= 1 && v <= 6) b0v[v] = t.y * (2.0f / 196.0f);
        }
        ob[(size_t)(r0 * 14 + 0) * 768] = a0[0] + a0[7] + a0[1] + a0[2] + a0[3] + a0[4] + a0[5] + a0[6];
        ob[(size_t)(r0 * 14 + 7) * 768] = a0[0] - a0[7] - a0[1] + a0[2] - a0[3] + a0[4] - a0[5] + a0[6];
        #pragma unroll
        for (int wp = 1; wp <= 6; ++wp) {
            float t1 = (wp & 1) ? (a0[0] - a0[7]) : (a0[0] + a0[7]);
            float t2 = 0.f;
            #pragma unroll
            for (int v = 1; v <= 6; ++v) {
                t1 = fmaf(a0[v],  C14[(v * wp) % 14], t1);
                t2 = fmaf(b0v[v], S14[(v * wp) % 14], t2);
            }
            ob[(size_t)(r0 * 14 + wp) * 768]      = t1 - t2;
            ob[(size_t)(r0 * 14 + 14 - wp) * 768] = t1 + t2;
        }
    }
    __syncthreads();                    // bar6: round-1 reads done

    // ---------------- P round 2: rows 7..13 = Q-R ----------------
    #pragma unroll
    for (int m = 0; m < 7; ++m)
        T[(m * 8 + wv) * 64 + ln] = make_float2(Qr[m], Qi[m]);
    __syncthreads();                    // bar7: P rows 7..13 visible
    {
        const int slot = (wv == 7) ? 0 : (wv + 1);
        const int orow = (wv == 7) ? 7 : r1;
        if (wv == 7 || two) {
            float a0[8], b0v[7];
            #pragma unroll
            for (int v = 0; v < 8; ++v) {
                float2 t = T[(slot * 8 + v) * 64 + ln];
                a0[v] = t.x * ((v == 0 || v == 7) ? (1.0f / 196.0f) : (2.0f / 196.0f));
                if (v >= 1 && v <= 6) b0v[v] = t.y * (2.0f / 196.0f);
            }
            ob[(size_t)(orow * 14 + 0) * 768] = a0[0] + a0[7] + a0[1] + a0[2] + a0[3] + a0[4] + a0[5] + a0[6];
            ob[(size_t)(orow * 14 + 7) * 768] = a0[0] - a0[7] - a0[1] + a0[2] - a0[3] + a0[4] - a0[5] + a0[6];
            #pragma unroll
            for (int wp = 1; wp <= 6; ++wp) {
                float t1 = (wp & 1) ? (a0[0] - a0[7]) : (a0[0] + a0[7]);
                float t2 = 0.f;
                #pragma unroll
                for (int v = 1; v <= 6; ++v) {
                    t1 = fmaf(a0[v],  C14[(v * wp) % 14], t1);
                    t2 = fmaf(b0v[v], S14[(v * wp) % 14], t2);
                }
                ob[(size_t)(orow * 14 + wp) * 768]      = t1 - t2;
                ob[(size_t)(orow * 14 + 14 - wp) * 768] = t1 + t2;
            }
        }
    }
}

extern "C" void kernel_launch(void* const* d_in, const int* in_sizes, int n_in,
                              void* d_out, int out_size, void* d_ws, size_t ws_size,
                              hipStream_t stream) {
    const float* x   = (const float*)d_in[0];
    const float* wgt = (const float*)d_in[1];
    float*       o   = (float*)d_out;

    const int B = in_sizes[0] / (196 * 768);   // 256
    dim3 grid(B * CTILES), block(NT);
    gfnet_filter<<<grid, block, 0, stream>>>(x, wgt, o);
}

// Round 7
// 71.184 us; speedup vs baseline: 1.2232x; 1.0447x over previous
//
#include <hip/hip_runtime.h>

// GFNet global filter: out = irfft2( rfft2(x) * W ), ortho norm, 14x14 spatial.
// x: (B=256, N=196, C=768) f32 ; W: (14, 8, C, 2) f32 ; out: (B, 196, C) f32.
//
// Dense small-DFT stages with compile-time twiddles, lane dim = channel.
// All stages use cos/sin symmetry pairing (j <-> 14-j); the h-FFT pair also
// uses radix-2 (14 = 2x7).
//
// 3-barrier structure (R3 5-bar=70.9us beat R6 7-bar=74.4us -> barriers are
// the binding constraint, not occupancy ceiling):
//   A (direct global) -> G transpose 1 round (compact: u=0,7 real) -> bar1
//   -> G column read -> B/H/C compute -> bar2 (convergent, ~free)
//   -> P transpose 1 round (full 57344B) -> bar3 -> D + stores.
// LDS 57344B -> 2 blocks/CU.
//
// __launch_bounds__(512,3): measured on this toolchain (512,8)/(512,6) force
// VGPR 32/40 -> scratch spills (WRITE_SIZE exceeded output bytes). (512,3)
// gave VGPR=44, WRITE exactly = output -> no spill.

static constexpr int CB     = 64;
static constexpr int NT     = 512;
static constexpr int CTILES = 768 / CB;   // 12

// cos/sin(2*pi*k/14)
static constexpr float C14[14] = {
     1.0f,
     0.90096886790241915f,  0.62348980185873359f,  0.22252093395631445f,
    -0.22252093395631434f, -0.62348980185873348f, -0.90096886790241915f,
    -1.0f,
    -0.90096886790241926f, -0.62348980185873371f, -0.22252093395631456f,
     0.22252093395631423f,  0.62348980185873337f,  0.90096886790241904f
};
static constexpr float S14[14] = {
     0.0f,
     0.43388373911755812f,  0.78183148246802980f,  0.97492791218182362f,
     0.97492791218182362f,  0.78183148246802991f,  0.43388373911755823f,
     0.0f,
    -0.43388373911755806f, -0.78183148246802958f, -0.97492791218182362f,
    -0.97492791218182373f, -0.78183148246802991f, -0.43388373911755834f
};

__global__ __launch_bounds__(NT, 3) void gfnet_filter(
    const float* __restrict__ x,
    const float* __restrict__ wgt,
    float* __restrict__ out)
{
    // 57344 B union buffer:
    //   G round (compact, 50176 B used): per row h (stride 896 floats):
    //     [0:64)=u0.re ; [64 + (u-1)*128) float2 for u=1..6 ; [832:896)=u7.re
    //   P round (full): float2 [m=0..13][v=0..7][64]
    __shared__ __align__(16) float LB[14336];
    float2* T = reinterpret_cast<float2*>(LB);

    const int bid = blockIdx.x;
    const int b   = bid / CTILES;
    const int ct  = bid - b * CTILES;
    const int c0  = ct * CB;
    const int tid = threadIdx.x;
    const int wv  = tid >> 6;
    const int ln  = tid & 63;
    const bool two = (wv < 6);
    const int r0 = wv;          // rows handled in phases A/D
    const int r1 = wv + 8;

    const float* xb = x + (size_t)b * 196 * 768 + c0 + ln;

    // ---------------- phase A: rfft along w (symmetry-paired) ----------------
    float A0r[8], A0i[7], A1r[8], A1i[7];   // i-index 1..6 used
    {
        float v0[14], v1[14];
        #pragma unroll
        for (int w = 0; w < 14; ++w) v0[w] = xb[(size_t)(r0 * 14 + w) * 768];
        if (two) {
            #pragma unroll
            for (int w = 0; w < 14; ++w) v1[w] = xb[(size_t)(r1 * 14 + w) * 768];
        }
        {
            float s[7], d[7];
            #pragma unroll
            for (int j = 1; j <= 6; ++j) { s[j] = v0[j] + v0[14 - j]; d[j] = v0[j] - v0[14 - j]; }
            A0r[0] = v0[0] + v0[7] + s[1] + s[2] + s[3] + s[4] + s[5] + s[6];
            A0r[7] = v0[0] - v0[7] - s[1] + s[2] - s[3] + s[4] - s[5] + s[6];
            #pragma unroll
            for (int u = 1; u <= 6; ++u) {
                float re = (u & 1) ? (v0[0] - v0[7]) : (v0[0] + v0[7]);
                float im = 0.f;
                #pragma unroll
                for (int j = 1; j <= 6; ++j) {
                    re = fmaf(s[j],  C14[(u * j) % 14], re);
                    im = fmaf(d[j], -S14[(u * j) % 14], im);
                }
                A0r[u] = re; A0i[u] = im;
            }
        }
        if (two) {
            float s[7], d[7];
            #pragma unroll
            for (int j = 1; j <= 6; ++j) { s[j] = v1[j] + v1[14 - j]; d[j] = v1[j] - v1[14 - j]; }
            A1r[0] = v1[0] + v1[7] + s[1] + s[2] + s[3] + s[4] + s[5] + s[6];
            A1r[7] = v1[0] - v1[7] - s[1] + s[2] - s[3] + s[4] - s[5] + s[6];
            #pragma unroll
            for (int u = 1; u <= 6; ++u) {
                float re = (u & 1) ? (v1[0] - v1[7]) : (v1[0] + v1[7]);
                float im = 0.f;
                #pragma unroll
                for (int j = 1; j <= 6; ++j) {
                    re = fmaf(s[j],  C14[(u * j) % 14], re);
                    im = fmaf(d[j], -S14[(u * j) % 14], im);
                }
                A1r[u] = re; A1i[u] = im;
            }
        }
    }

    // ---------------- G transpose (compact, single round) ----------------
    {
        float* g0 = LB + r0 * 896;
        g0[ln]       = A0r[0];
        g0[832 + ln] = A0r[7];
        #pragma unroll
        for (int u = 1; u <= 6; ++u)
            reinterpret_cast<float2*>(g0 + 64 + (u - 1) * 128)[ln] = make_float2(A0r[u], A0i[u]);
        if (two) {
            float* g1 = LB + r1 * 896;
            g1[ln]       = A1r[0];
            g1[832 + ln] = A1r[7];
            #pragma unroll
            for (int u = 1; u <= 6; ++u)
                reinterpret_cast<float2*>(g1 + 64 + (u - 1) * 128)[ln] = make_float2(A1r[u], A1i[u]);
        }
    }

    // hoist weight loads: issue before the barrier so latency overlaps the wait
    float wr[14], wi[14];
    {
        const float2* wb = reinterpret_cast<const float2*>(wgt) + (size_t)wv * 768 + c0 + ln;
        #pragma unroll
        for (int k = 0; k < 14; ++k) {
            const float2 t = wb[(size_t)k * (8 * 768)];
            wr[k] = t.x; wi[k] = t.y;
        }
    }

    __syncthreads();                    // bar1: G visible

    float gr[14], gi[14];
    if (wv == 0) {
        #pragma unroll
        for (int h = 0; h < 14; ++h) { gr[h] = LB[h * 896 + ln]; gi[h] = 0.f; }
    } else if (wv == 7) {
        #pragma unroll
        for (int h = 0; h < 14; ++h) { gr[h] = LB[h * 896 + 832 + ln]; gi[h] = 0.f; }
    } else {
        #pragma unroll
        for (int h = 0; h < 14; ++h) {
            float2 t = reinterpret_cast<float2*>(LB + h * 896 + 64 + (wv - 1) * 128)[ln];
            gr[h] = t.x; gi[h] = t.y;
        }
    }

    // ---------------- phase B: a[k] = FFT_h(g), radix-2 + pairing ----------------
    float esr[3], esi[3], edr[3], edi[3], osr[3], osi[3], odr[3], odi[3];
    #pragma unroll
    for (int i = 0; i < 3; ++i) {
        int j = 2 * (i + 1);
        esr[i] = gr[j] + gr[14 - j]; esi[i] = gi[j] + gi[14 - j];
        edr[i] = gr[j] - gr[14 - j]; edi[i] = gi[j] - gi[14 - j];
        j = 2 * i + 1;
        osr[i] = gr[j] + gr[14 - j]; osi[i] = gi[j] + gi[14 - j];
        odr[i] = gr[j] - gr[14 - j]; odi[i] = gi[j] - gi[14 - j];
    }
    float Ekr[7], Eki[7], Okr[7], Oki[7];
    Ekr[0] = gr[0] + esr[0] + esr[1] + esr[2];
    Eki[0] = gi[0] + esi[0] + esi[1] + esi[2];
    Okr[0] = gr[7] + osr[0] + osr[1] + osr[2];
    Oki[0] = gi[7] + osi[0] + osi[1] + osi[2];
    #pragma unroll
    for (int k = 1; k <= 6; ++k) {
        float er = gr[0], ei = gi[0];
        #pragma unroll
        for (int i = 0; i < 3; ++i) {
            const int j = 2 * (i + 1);
            const float c = C14[(j * k) % 14], s2 = S14[(j * k) % 14];
            er = fmaf(esr[i], c, er); er = fmaf(edi[i],  s2, er);
            ei = fmaf(esi[i], c, ei); ei = fmaf(edr[i], -s2, ei);
        }
        Ekr[k] = er; Eki[k] = ei;
        float onr = (k & 1) ? -gr[7] : gr[7];
        float oni = (k & 1) ? -gi[7] : gi[7];
        #pragma unroll
        for (int i = 0; i < 3; ++i) {
            const int j = 2 * i + 1;
            const float c = C14[(j * k) % 14], s2 = S14[(j * k) % 14];
            onr = fmaf(osr[i], c, onr); onr = fmaf(odi[i],  s2, onr);
            oni = fmaf(osi[i], c, oni); oni = fmaf(odr[i], -s2, oni);
        }
        Okr[k] = onr; Oki[k] = oni;
    }

    // ---------------- weight multiply: H[k] = a[k] * w[k] ----------------
    float Hr[14], Hi[14];
    #pragma unroll
    for (int k = 0; k < 7; ++k) {
        const float ar = Ekr[k] + Okr[k], ai = Eki[k] + Oki[k];
        const float br = Ekr[k] - Okr[k], bi = Eki[k] - Oki[k];
        Hr[k]     = fmaf(ar, wr[k],     -(ai * wi[k]));
        Hi[k]     = fmaf(ar, wi[k],       ai * wr[k]);
        Hr[k + 7] = fmaf(br, wr[k + 7], -(bi * wi[k + 7]));
        Hi[k + 7] = fmaf(br, wi[k + 7],   bi * wr[k + 7]);
    }

    // ---------------- phase C: P = IFFT_h(H), radix-2 + pairing ----------------
    float qsr[3], qsi[3], qdr[3], qdi[3], rsr[3], rsi[3], rdr[3], rdi[3];
    #pragma unroll
    for (int i = 0; i < 3; ++i) {
        int j = 2 * (i + 1);
        qsr[i] = Hr[j] + Hr[14 - j]; qsi[i] = Hi[j] + Hi[14 - j];
        qdr[i] = Hr[j] - Hr[14 - j]; qdi[i] = Hi[j] - Hi[14 - j];
        j = 2 * i + 1;
        rsr[i] = Hr[j] + Hr[14 - j]; rsi[i] = Hi[j] + Hi[14 - j];
        rdr[i] = Hr[j] - Hr[14 - j]; rdi[i] = Hi[j] - Hi[14 - j];
    }
    float Qr[7], Qi[7], Rr[7], Ri[7];
    Qr[0] = Hr[0] + qsr[0] + qsr[1] + qsr[2];
    Qi[0] = Hi[0] + qsi[0] + qsi[1] + qsi[2];
    Rr[0] = Hr[7] + rsr[0] + rsr[1] + rsr[2];
    Ri[0] = Hi[7] + rsi[0] + rsi[1] + rsi[2];
    #pragma unroll
    for (int m = 1; m <= 6; ++m) {
        float qr = Hr[0], qi2 = Hi[0];
        #pragma unroll
        for (int i = 0; i < 3; ++i) {
            const int j = 2 * (i + 1);
            const float c = C14[(j * m) % 14], s2 = S14[(j * m) % 14];
            qr  = fmaf(qsr[i], c, qr);  qr  = fmaf(qdi[i], -s2, qr);
            qi2 = fmaf(qsi[i], c, qi2); qi2 = fmaf(qdr[i],  s2, qi2);
        }
        Qr[m] = qr; Qi[m] = qi2;
        float rr = (m & 1) ? -Hr[7] : Hr[7];
        float ri2 = (m & 1) ? -Hi[7] : Hi[7];
        #pragma unroll
        for (int i = 0; i < 3; ++i) {
            const int j = 2 * i + 1;
            const float c = C14[(j * m) % 14], s2 = S14[(j * m) % 14];
            rr  = fmaf(rsr[i], c, rr);  rr  = fmaf(rdi[i], -s2, rr);
            ri2 = fmaf(rsi[i], c, ri2); ri2 = fmaf(rdr[i],  s2, ri2);
        }
        Rr[m] = rr; Ri[m] = ri2;
    }

    __syncthreads();                    // bar2: all G reads done (convergent: placed
                                        // right after the long B/H/C compute)

    // ---------------- P transpose (full, single round) ----------------
    #pragma unroll
    for (int m = 0; m < 7; ++m) {
        T[(m * 8 + wv) * 64 + ln]       = make_float2(Qr[m] + Rr[m], Qi[m] + Ri[m]);
        T[((m + 7) * 8 + wv) * 64 + ln] = make_float2(Qr[m] - Rr[m], Qi[m] - Ri[m]);
    }
    __syncthreads();                    // bar3: P visible

    // ---------------- phase D: inverse rfft along w for rows r0 (and r1) ----------------
    float* ob = out + (size_t)b * 196 * 768 + c0 + ln;
    #pragma unroll
    for (int rr = 0; rr < 2; ++rr) {
        const int row = rr ? r1 : r0;
        if (rr == 0 || two) {
            float a0[8], b0v[7];
            #pragma unroll
            for (int v = 0; v < 8; ++v) {
                float2 t = T[(row * 8 + v) * 64 + ln];
                a0[v] = t.x * ((v == 0 || v == 7) ? (1.0f / 196.0f) : (2.0f / 196.0f));
                if (v >= 1 && v <= 6) b0v[v] = t.y * (2.0f / 196.0f);
            }
            ob[(size_t)(row * 14 + 0) * 768] = a0[0] + a0[7] + a0[1] + a0[2] + a0[3] + a0[4] + a0[5] + a0[6];
            ob[(size_t)(row * 14 + 7) * 768] = a0[0] - a0[7] - a0[1] + a0[2] - a0[3] + a0[4] - a0[5] + a0[6];
            #pragma unroll
            for (int wp = 1; wp <= 6; ++wp) {
                float t1 = (wp & 1) ? (a0[0] - a0[7]) : (a0[0] + a0[7]);
                float t2 = 0.f;
                #pragma unroll
                for (int v = 1; v <= 6; ++v) {
                    t1 = fmaf(a0[v],  C14[(v * wp) % 14], t1);
                    t2 = fmaf(b0v[v], S14[(v * wp) % 14], t2);
                }
                ob[(size_t)(row * 14 + wp) * 768]      = t1 - t2;
                ob[(size_t)(row * 14 + 14 - wp) * 768] = t1 + t2;
            }
        }
    }
}

extern "C" void kernel_launch(void* const* d_in, const int* in_sizes, int n_in,
                              void* d_out, int out_size, void* d_ws, size_t ws_size,
                              hipStream_t stream) {
    const float* x   = (const float*)d_in[0];
    const float* wgt = (const float*)d_in[1];
    float*       o   = (float*)d_out;

    const int B = in_sizes[0] / (196 * 768);   // 256
    dim3 grid(B * CTILES), block(NT);
    gfnet_filter<<<grid, block, 0, stream>>>(x, wgt, o);
}

// Round 8
// 69.048 us; speedup vs baseline: 1.2610x; 1.0309x over previous
//
#include <hip/hip_runtime.h>
#include <hip/hip_bf16.h>

// GFNet global filter: out = irfft2( rfft2(x) * W ), ortho norm, 14x14 spatial.
// x: (B=256, N=196, C=768) f32 ; W: (14, 8, C, 2) f32 ; out: (B, 196, C) f32.
//
// Dense small-DFT stages with compile-time twiddles, lane dim = channel.
// All stages use cos/sin symmetry pairing (j <-> 14-j); the h-FFT pair also
// uses radix-2 (14 = 2x7).
//
// R8: bf16-packed LDS transposes. Each complex value packs into one dword
// (cvt_pk_bf16), so BOTH transposes are full single-round [14][8][64] dwords
// = 28672 B union buffer. This keeps R7's 3-barrier schedule AND the
// 4-blocks/CU ceiling (32 waves = 100%) that R6's layout had.
// Error budget: bf16 at |G|~4, |P|~1.5 adds ~3e-4 to output absmax
// (threshold 3.2e-3; f32 version measured 4.9e-4).
//
// __launch_bounds__(512,3): measured on this toolchain (512,8)/(512,6) force
// VGPR 32/40 -> scratch spills (WRITE_SIZE exceeded output bytes). (512,3)
// gave VGPR 44-52, WRITE exactly = output -> no spill.

static constexpr int CB     = 64;
static constexpr int NT     = 512;
static constexpr int CTILES = 768 / CB;   // 12

// cos/sin(2*pi*k/14)
static constexpr float C14[14] = {
     1.0f,
     0.90096886790241915f,  0.62348980185873359f,  0.22252093395631445f,
    -0.22252093395631434f, -0.62348980185873348f, -0.90096886790241915f,
    -1.0f,
    -0.90096886790241926f, -0.62348980185873371f, -0.22252093395631456f,
     0.22252093395631423f,  0.62348980185873337f,  0.90096886790241904f
};
static constexpr float S14[14] = {
     0.0f,
     0.43388373911755812f,  0.78183148246802980f,  0.97492791218182362f,
     0.97492791218182362f,  0.78183148246802991f,  0.43388373911755823f,
     0.0f,
    -0.43388373911755806f, -0.78183148246802958f, -0.97492791218182362f,
    -0.97492791218182373f, -0.78183148246802991f, -0.43388373911755834f
};

__device__ __forceinline__ uint32_t pk_bf16(float re, float im) {
    union { __hip_bfloat162 h2; uint32_t u; } cv;
    cv.h2 = __float22bfloat162_rn(make_float2(re, im));
    return cv.u;
}
__device__ __forceinline__ float2 up_bf16(uint32_t v) {
    return make_float2(__uint_as_float(v << 16),
                       __uint_as_float(v & 0xffff0000u));
}

__global__ __launch_bounds__(NT, 3) void gfnet_filter(
    const float* __restrict__ x,
    const float* __restrict__ wgt,
    float* __restrict__ out)
{
    // 28672 B union buffer, packed bf16 complex:
    //   G round: [h=0..13][u=0..7][64]   (u=0,7 carry im=0)
    //   P round: [row=0..13][v=0..7][64]
    __shared__ uint32_t T[14 * 8 * 64];

    const int bid = blockIdx.x;
    const int b   = bid / CTILES;
    const int ct  = bid - b * CTILES;
    const int c0  = ct * CB;
    const int tid = threadIdx.x;
    const int wv  = tid >> 6;
    const int ln  = tid & 63;
    const bool two = (wv < 6);
    const int r0 = wv;          // rows handled in phases A/D
    const int r1 = wv + 8;

    const float* xb = x + (size_t)b * 196 * 768 + c0 + ln;

    // ---------------- phase A: rfft along w (symmetry-paired) ----------------
    float A0r[8], A0i[7], A1r[8], A1i[7];   // i-index 1..6 used
    {
        float v0[14], v1[14];
        #pragma unroll
        for (int w = 0; w < 14; ++w) v0[w] = xb[(size_t)(r0 * 14 + w) * 768];
        if (two) {
            #pragma unroll
            for (int w = 0; w < 14; ++w) v1[w] = xb[(size_t)(r1 * 14 + w) * 768];
        }
        {
            float s[7], d[7];
            #pragma unroll
            for (int j = 1; j <= 6; ++j) { s[j] = v0[j] + v0[14 - j]; d[j] = v0[j] - v0[14 - j]; }
            A0r[0] = v0[0] + v0[7] + s[1] + s[2] + s[3] + s[4] + s[5] + s[6];
            A0r[7] = v0[0] - v0[7] - s[1] + s[2] - s[3] + s[4] - s[5] + s[6];
            #pragma unroll
            for (int u = 1; u <= 6; ++u) {
                float re = (u & 1) ? (v0[0] - v0[7]) : (v0[0] + v0[7]);
                float im = 0.f;
                #pragma unroll
                for (int j = 1; j <= 6; ++j) {
                    re = fmaf(s[j],  C14[(u * j) % 14], re);
                    im = fmaf(d[j], -S14[(u * j) % 14], im);
                }
                A0r[u] = re; A0i[u] = im;
            }
        }
        if (two) {
            float s[7], d[7];
            #pragma unroll
            for (int j = 1; j <= 6; ++j) { s[j] = v1[j] + v1[14 - j]; d[j] = v1[j] - v1[14 - j]; }
            A1r[0] = v1[0] + v1[7] + s[1] + s[2] + s[3] + s[4] + s[5] + s[6];
            A1r[7] = v1[0] - v1[7] - s[1] + s[2] - s[3] + s[4] - s[5] + s[6];
            #pragma unroll
            for (int u = 1; u <= 6; ++u) {
                float re = (u & 1) ? (v1[0] - v1[7]) : (v1[0] + v1[7]);
                float im = 0.f;
                #pragma unroll
                for (int j = 1; j <= 6; ++j) {
                    re = fmaf(s[j],  C14[(u * j) % 14], re);
                    im = fmaf(d[j], -S14[(u * j) % 14], im);
                }
                A1r[u] = re; A1i[u] = im;
            }
        }
    }

    // ---------------- G transpose (packed bf16, single round) ----------------
    #pragma unroll
    for (int u = 0; u < 8; ++u)
        T[(r0 * 8 + u) * 64 + ln] =
            pk_bf16(A0r[u], (u >= 1 && u <= 6) ? A0i[u] : 0.f);
    if (two) {
        #pragma unroll
        for (int u = 0; u < 8; ++u)
            T[(r1 * 8 + u) * 64 + ln] =
                pk_bf16(A1r[u], (u >= 1 && u <= 6) ? A1i[u] : 0.f);
    }

    // hoist weight loads: issue before the barrier so latency overlaps the wait
    float wr[14], wi[14];
    {
        const float2* wb = reinterpret_cast<const float2*>(wgt) + (size_t)wv * 768 + c0 + ln;
        #pragma unroll
        for (int k = 0; k < 14; ++k) {
            const float2 t = wb[(size_t)k * (8 * 768)];
            wr[k] = t.x; wi[k] = t.y;
        }
    }

    __syncthreads();                    // bar1: G visible

    float gr[14], gi[14];
    #pragma unroll
    for (int h = 0; h < 14; ++h) {
        float2 t = up_bf16(T[(h * 8 + wv) * 64 + ln]);
        gr[h] = t.x; gi[h] = t.y;
    }

    // ---------------- phase B: a[k] = FFT_h(g), radix-2 + pairing ----------------
    float esr[3], esi[3], edr[3], edi[3], osr[3], osi[3], odr[3], odi[3];
    #pragma unroll
    for (int i = 0; i < 3; ++i) {
        int j = 2 * (i + 1);
        esr[i] = gr[j] + gr[14 - j]; esi[i] = gi[j] + gi[14 - j];
        edr[i] = gr[j] - gr[14 - j]; edi[i] = gi[j] - gi[14 - j];
        j = 2 * i + 1;
        osr[i] = gr[j] + gr[14 - j]; osi[i] = gi[j] + gi[14 - j];
        odr[i] = gr[j] - gr[14 - j]; odi[i] = gi[j] - gi[14 - j];
    }
    float Ekr[7], Eki[7], Okr[7], Oki[7];
    Ekr[0] = gr[0] + esr[0] + esr[1] + esr[2];
    Eki[0] = gi[0] + esi[0] + esi[1] + esi[2];
    Okr[0] = gr[7] + osr[0] + osr[1] + osr[2];
    Oki[0] = gi[7] + osi[0] + osi[1] + osi[2];
    #pragma unroll
    for (int k = 1; k <= 6; ++k) {
        float er = gr[0], ei = gi[0];
        #pragma unroll
        for (int i = 0; i < 3; ++i) {
            const int j = 2 * (i + 1);
            const float c = C14[(j * k) % 14], s2 = S14[(j * k) % 14];
            er = fmaf(esr[i], c, er); er = fmaf(edi[i],  s2, er);
            ei = fmaf(esi[i], c, ei); ei = fmaf(edr[i], -s2, ei);
        }
        Ekr[k] = er; Eki[k] = ei;
        float onr = (k & 1) ? -gr[7] : gr[7];
        float oni = (k & 1) ? -gi[7] : gi[7];
        #pragma unroll
        for (int i = 0; i < 3; ++i) {
            const int j = 2 * i + 1;
            const float c = C14[(j * k) % 14], s2 = S14[(j * k) % 14];
            onr = fmaf(osr[i], c, onr); onr = fmaf(odi[i],  s2, onr);
            oni = fmaf(osi[i], c, oni); oni = fmaf(odr[i], -s2, oni);
        }
        Okr[k] = onr; Oki[k] = oni;
    }

    // ---------------- weight multiply: H[k] = a[k] * w[k] ----------------
    float Hr[14], Hi[14];
    #pragma unroll
    for (int k = 0; k < 7; ++k) {
        const float ar = Ekr[k] + Okr[k], ai = Eki[k] + Oki[k];
        const float br = Ekr[k] - Okr[k], bi = Eki[k] - Oki[k];
        Hr[k]     = fmaf(ar, wr[k],     -(ai * wi[k]));
        Hi[k]     = fmaf(ar, wi[k],       ai * wr[k]);
        Hr[k + 7] = fmaf(br, wr[k + 7], -(bi * wi[k + 7]));
        Hi[k + 7] = fmaf(br, wi[k + 7],   bi * wr[k + 7]);
    }

    // ---------------- phase C: P = IFFT_h(H), radix-2 + pairing ----------------
    float qsr[3], qsi[3], qdr[3], qdi[3], rsr[3], rsi[3], rdr[3], rdi[3];
    #pragma unroll
    for (int i = 0; i < 3; ++i) {
        int j = 2 * (i + 1);
        qsr[i] = Hr[j] + Hr[14 - j]; qsi[i] = Hi[j] + Hi[14 - j];
        qdr[i] = Hr[j] - Hr[14 - j]; qdi[i] = Hi[j] - Hi[14 - j];
        j = 2 * i + 1;
        rsr[i] = Hr[j] + Hr[14 - j]; rsi[i] = Hi[j] + Hi[14 - j];
        rdr[i] = Hr[j] - Hr[14 - j]; rdi[i] = Hi[j] - Hi[14 - j];
    }
    float Qr[7], Qi[7], Rr[7], Ri[7];
    Qr[0] = Hr[0] + qsr[0] + qsr[1] + qsr[2];
    Qi[0] = Hi[0] + qsi[0] + qsi[1] + qsi[2];
    Rr[0] = Hr[7] + rsr[0] + rsr[1] + rsr[2];
    Ri[0] = Hi[7] + rsi[0] + rsi[1] + rsi[2];
    #pragma unroll
    for (int m = 1; m <= 6; ++m) {
        float qr = Hr[0], qi2 = Hi[0];
        #pragma unroll
        for (int i = 0; i < 3; ++i) {
            const int j = 2 * (i + 1);
            const float c = C14[(j * m) % 14], s2 = S14[(j * m) % 14];
            qr  = fmaf(qsr[i], c, qr);  qr  = fmaf(qdi[i], -s2, qr);
            qi2 = fmaf(qsi[i], c, qi2); qi2 = fmaf(qdr[i],  s2, qi2);
        }
        Qr[m] = qr; Qi[m] = qi2;
        float rr = (m & 1) ? -Hr[7] : Hr[7];
        float ri2 = (m & 1) ? -Hi[7] : Hi[7];
        #pragma unroll
        for (int i = 0; i < 3; ++i) {
            const int j = 2 * i + 1;
            const float c = C14[(j * m) % 14], s2 = S14[(j * m) % 14];
            rr  = fmaf(rsr[i], c, rr);  rr  = fmaf(rdi[i], -s2, rr);
            ri2 = fmaf(rsi[i], c, ri2); ri2 = fmaf(rdr[i],  s2, ri2);
        }
        Rr[m] = rr; Ri[m] = ri2;
    }

    __syncthreads();                    // bar2: all G reads done (convergent: placed
                                        // right after the long B/H/C compute)

    // ---------------- P transpose (packed bf16, single round) ----------------
    #pragma unroll
    for (int m = 0; m < 7; ++m) {
        T[(m * 8 + wv) * 64 + ln]       = pk_bf16(Qr[m] + Rr[m], Qi[m] + Ri[m]);
        T[((m + 7) * 8 + wv) * 64 + ln] = pk_bf16(Qr[m] - Rr[m], Qi[m] - Ri[m]);
    }
    __syncthreads();                    // bar3: P visible

    // ---------------- phase D: inverse rfft along w for rows r0 (and r1) ----------------
    float* ob = out + (size_t)b * 196 * 768 + c0 + ln;
    #pragma unroll
    for (int rr = 0; rr < 2; ++rr) {
        const int row = rr ? r1 : r0;
        if (rr == 0 || two) {
            float a0[8], b0v[7];
            #pragma unroll
            for (int v = 0; v < 8; ++v) {
                float2 t = up_bf16(T[(row * 8 + v) * 64 + ln]);
                a0[v] = t.x * ((v == 0 || v == 7) ? (1.0f / 196.0f) : (2.0f / 196.0f));
                if (v >= 1 && v <= 6) b0v[v] = t.y * (2.0f / 196.0f);
            }
            ob[(size_t)(row * 14 + 0) * 768] = a0[0] + a0[7] + a0[1] + a0[2] + a0[3] + a0[4] + a0[5] + a0[6];
            ob[(size_t)(row * 14 + 7) * 768] = a0[0] - a0[7] - a0[1] + a0[2] - a0[3] + a0[4] - a0[5] + a0[6];
            #pragma unroll
            for (int wp = 1; wp <= 6; ++wp) {
                float t1 = (wp & 1) ? (a0[0] - a0[7]) : (a0[0] + a0[7]);
                float t2 = 0.f;
                #pragma unroll
                for (int v = 1; v <= 6; ++v) {
                    t1 = fmaf(a0[v],  C14[(v * wp) % 14], t1);
                    t2 = fmaf(b0v[v], S14[(v * wp) % 14], t2);
                }
                ob[(size_t)(row * 14 + wp) * 768]      = t1 - t2;
                ob[(size_t)(row * 14 + 14 - wp) * 768] = t1 + t2;
            }
        }
    }
}

extern "C" void kernel_launch(void* const* d_in, const int* in_sizes, int n_in,
                              void* d_out, int out_size, void* d_ws, size_t ws_size,
                              hipStream_t stream) {
    const float* x   = (const float*)d_in[0];
    const float* wgt = (const float*)d_in[1];
    float*       o   = (float*)d_out;

    const int B = in_sizes[0] / (196 * 768);   // 256
    dim3 grid(B * CTILES), block(NT);
    gfnet_filter<<<grid, block, 0, stream>>>(x, wgt, o);
}

// Round 9
// 56.767 us; speedup vs baseline: 1.5338x; 1.2163x over previous
//
#include <hip/hip_runtime.h>
#include <hip/hip_bf16.h>

// GFNet global filter: out = irfft2( rfft2(x) * W ), ortho norm, 14x14 spatial.
// x: (B=256, N=196, C=768) f32 ; W: (14, 8, C, 2) f32 ; out: (B, 196, C) f32.
//
// Dense small-DFT stages with compile-time twiddles, lane dim = channel.
// All stages use cos/sin symmetry pairing (j <-> 14-j); the h-FFT pair also
// uses radix-2 (14 = 2x7).
//
// R8 structure (best: 69.0us): bf16-packed LDS transposes, single-round each,
// 3 barriers, 28672 B union buffer.
//
// R9: NON-TEMPORAL output stores. Steady-state FETCH_SIZE was 76 MB although
// x = 154 MB: the 150 MB output write stream write-allocates in the 256 MB
// LLC each replay and evicts half of x (154+150 > 256; miss ~ x-(LLC-out)
// matches measured 76 MB). Output is never re-read -> nt stores stop the
// pollution, x becomes fully LLC-resident, HBM traffic/replay 226 -> ~155 MB.
//
// __launch_bounds__(512,3): measured on this toolchain (512,8)/(512,6) force
// VGPR 32/40 -> scratch spills (WRITE_SIZE exceeded output bytes). (512,3)
// gave VGPR 44-52, WRITE exactly = output -> no spill.

static constexpr int CB     = 64;
static constexpr int NT     = 512;
static constexpr int CTILES = 768 / CB;   // 12

// cos/sin(2*pi*k/14)
static constexpr float C14[14] = {
     1.0f,
     0.90096886790241915f,  0.62348980185873359f,  0.22252093395631445f,
    -0.22252093395631434f, -0.62348980185873348f, -0.90096886790241915f,
    -1.0f,
    -0.90096886790241926f, -0.62348980185873371f, -0.22252093395631456f,
     0.22252093395631423f,  0.62348980185873337f,  0.90096886790241904f
};
static constexpr float S14[14] = {
     0.0f,
     0.43388373911755812f,  0.78183148246802980f,  0.97492791218182362f,
     0.97492791218182362f,  0.78183148246802991f,  0.43388373911755823f,
     0.0f,
    -0.43388373911755806f, -0.78183148246802958f, -0.97492791218182362f,
    -0.97492791218182373f, -0.78183148246802991f, -0.43388373911755834f
};

__device__ __forceinline__ uint32_t pk_bf16(float re, float im) {
    union { __hip_bfloat162 h2; uint32_t u; } cv;
    cv.h2 = __float22bfloat162_rn(make_float2(re, im));
    return cv.u;
}
__device__ __forceinline__ float2 up_bf16(uint32_t v) {
    return make_float2(__uint_as_float(v << 16),
                       __uint_as_float(v & 0xffff0000u));
}

__global__ __launch_bounds__(NT, 3) void gfnet_filter(
    const float* __restrict__ x,
    const float* __restrict__ wgt,
    float* __restrict__ out)
{
    // 28672 B union buffer, packed bf16 complex:
    //   G round: [h=0..13][u=0..7][64]   (u=0,7 carry im=0)
    //   P round: [row=0..13][v=0..7][64]
    __shared__ uint32_t T[14 * 8 * 64];

    const int bid = blockIdx.x;
    const int b   = bid / CTILES;
    const int ct  = bid - b * CTILES;
    const int c0  = ct * CB;
    const int tid = threadIdx.x;
    const int wv  = tid >> 6;
    const int ln  = tid & 63;
    const bool two = (wv < 6);
    const int r0 = wv;          // rows handled in phases A/D
    const int r1 = wv + 8;

    const float* xb = x + (size_t)b * 196 * 768 + c0 + ln;

    // ---------------- phase A: rfft along w (symmetry-paired) ----------------
    float A0r[8], A0i[7], A1r[8], A1i[7];   // i-index 1..6 used
    {
        float v0[14], v1[14];
        #pragma unroll
        for (int w = 0; w < 14; ++w) v0[w] = xb[(size_t)(r0 * 14 + w) * 768];
        if (two) {
            #pragma unroll
            for (int w = 0; w < 14; ++w) v1[w] = xb[(size_t)(r1 * 14 + w) * 768];
        }
        {
            float s[7], d[7];
            #pragma unroll
            for (int j = 1; j <= 6; ++j) { s[j] = v0[j] + v0[14 - j]; d[j] = v0[j] - v0[14 - j]; }
            A0r[0] = v0[0] + v0[7] + s[1] + s[2] + s[3] + s[4] + s[5] + s[6];
            A0r[7] = v0[0] - v0[7] - s[1] + s[2] - s[3] + s[4] - s[5] + s[6];
            #pragma unroll
            for (int u = 1; u <= 6; ++u) {
                float re = (u & 1) ? (v0[0] - v0[7]) : (v0[0] + v0[7]);
                float im = 0.f;
                #pragma unroll
                for (int j = 1; j <= 6; ++j) {
                    re = fmaf(s[j],  C14[(u * j) % 14], re);
                    im = fmaf(d[j], -S14[(u * j) % 14], im);
                }
                A0r[u] = re; A0i[u] = im;
            }
        }
        if (two) {
            float s[7], d[7];
            #pragma unroll
            for (int j = 1; j <= 6; ++j) { s[j] = v1[j] + v1[14 - j]; d[j] = v1[j] - v1[14 - j]; }
            A1r[0] = v1[0] + v1[7] + s[1] + s[2] + s[3] + s[4] + s[5] + s[6];
            A1r[7] = v1[0] - v1[7] - s[1] + s[2] - s[3] + s[4] - s[5] + s[6];
            #pragma unroll
            for (int u = 1; u <= 6; ++u) {
                float re = (u & 1) ? (v1[0] - v1[7]) : (v1[0] + v1[7]);
                float im = 0.f;
                #pragma unroll
                for (int j = 1; j <= 6; ++j) {
                    re = fmaf(s[j],  C14[(u * j) % 14], re);
                    im = fmaf(d[j], -S14[(u * j) % 14], im);
                }
                A1r[u] = re; A1i[u] = im;
            }
        }
    }

    // ---------------- G transpose (packed bf16, single round) ----------------
    #pragma unroll
    for (int u = 0; u < 8; ++u)
        T[(r0 * 8 + u) * 64 + ln] =
            pk_bf16(A0r[u], (u >= 1 && u <= 6) ? A0i[u] : 0.f);
    if (two) {
        #pragma unroll
        for (int u = 0; u < 8; ++u)
            T[(r1 * 8 + u) * 64 + ln] =
                pk_bf16(A1r[u], (u >= 1 && u <= 6) ? A1i[u] : 0.f);
    }

    // hoist weight loads: issue before the barrier so latency overlaps the wait
    float wr[14], wi[14];
    {
        const float2* wb = reinterpret_cast<const float2*>(wgt) + (size_t)wv * 768 + c0 + ln;
        #pragma unroll
        for (int k = 0; k < 14; ++k) {
            const float2 t = wb[(size_t)k * (8 * 768)];
            wr[k] = t.x; wi[k] = t.y;
        }
    }

    __syncthreads();                    // bar1: G visible

    float gr[14], gi[14];
    #pragma unroll
    for (int h = 0; h < 14; ++h) {
        float2 t = up_bf16(T[(h * 8 + wv) * 64 + ln]);
        gr[h] = t.x; gi[h] = t.y;
    }

    // ---------------- phase B: a[k] = FFT_h(g), radix-2 + pairing ----------------
    float esr[3], esi[3], edr[3], edi[3], osr[3], osi[3], odr[3], odi[3];
    #pragma unroll
    for (int i = 0; i < 3; ++i) {
        int j = 2 * (i + 1);
        esr[i] = gr[j] + gr[14 - j]; esi[i] = gi[j] + gi[14 - j];
        edr[i] = gr[j] - gr[14 - j]; edi[i] = gi[j] - gi[14 - j];
        j = 2 * i + 1;
        osr[i] = gr[j] + gr[14 - j]; osi[i] = gi[j] + gi[14 - j];
        odr[i] = gr[j] - gr[14 - j]; odi[i] = gi[j] - gi[14 - j];
    }
    float Ekr[7], Eki[7], Okr[7], Oki[7];
    Ekr[0] = gr[0] + esr[0] + esr[1] + esr[2];
    Eki[0] = gi[0] + esi[0] + esi[1] + esi[2];
    Okr[0] = gr[7] + osr[0] + osr[1] + osr[2];
    Oki[0] = gi[7] + osi[0] + osi[1] + osi[2];
    #pragma unroll
    for (int k = 1; k <= 6; ++k) {
        float er = gr[0], ei = gi[0];
        #pragma unroll
        for (int i = 0; i < 3; ++i) {
            const int j = 2 * (i + 1);
            const float c = C14[(j * k) % 14], s2 = S14[(j * k) % 14];
            er = fmaf(esr[i], c, er); er = fmaf(edi[i],  s2, er);
            ei = fmaf(esi[i], c, ei); ei = fmaf(edr[i], -s2, ei);
        }
        Ekr[k] = er; Eki[k] = ei;
        float onr = (k & 1) ? -gr[7] : gr[7];
        float oni = (k & 1) ? -gi[7] : gi[7];
        #pragma unroll
        for (int i = 0; i < 3; ++i) {
            const int j = 2 * i + 1;
            const float c = C14[(j * k) % 14], s2 = S14[(j * k) % 14];
            onr = fmaf(osr[i], c, onr); onr = fmaf(odi[i],  s2, onr);
            oni = fmaf(osi[i], c, oni); oni = fmaf(odr[i], -s2, oni);
        }
        Okr[k] = onr; Oki[k] = oni;
    }

    // ---------------- weight multiply: H[k] = a[k] * w[k] ----------------
    float Hr[14], Hi[14];
    #pragma unroll
    for (int k = 0; k < 7; ++k) {
        const float ar = Ekr[k] + Okr[k], ai = Eki[k] + Oki[k];
        const float br = Ekr[k] - Okr[k], bi = Eki[k] - Oki[k];
        Hr[k]     = fmaf(ar, wr[k],     -(ai * wi[k]));
        Hi[k]     = fmaf(ar, wi[k],       ai * wr[k]);
        Hr[k + 7] = fmaf(br, wr[k + 7], -(bi * wi[k + 7]));
        Hi[k + 7] = fmaf(br, wi[k + 7],   bi * wr[k + 7]);
    }

    // ---------------- phase C: P = IFFT_h(H), radix-2 + pairing ----------------
    float qsr[3], qsi[3], qdr[3], qdi[3], rsr[3], rsi[3], rdr[3], rdi[3];
    #pragma unroll
    for (int i = 0; i < 3; ++i) {
        int j = 2 * (i + 1);
        qsr[i] = Hr[j] + Hr[14 - j]; qsi[i] = Hi[j] + Hi[14 - j];
        qdr[i] = Hr[j] - Hr[14 - j]; qdi[i] = Hi[j] - Hi[14 - j];
        j = 2 * i + 1;
        rsr[i] = Hr[j] + Hr[14 - j]; rsi[i] = Hi[j] + Hi[14 - j];
        rdr[i] = Hr[j] - Hr[14 - j]; rdi[i] = Hi[j] - Hi[14 - j];
    }
    float Qr[7], Qi[7], Rr[7], Ri[7];
    Qr[0] = Hr[0] + qsr[0] + qsr[1] + qsr[2];
    Qi[0] = Hi[0] + qsi[0] + qsi[1] + qsi[2];
    Rr[0] = Hr[7] + rsr[0] + rsr[1] + rsr[2];
    Ri[0] = Hi[7] + rsi[0] + rsi[1] + rsi[2];
    #pragma unroll
    for (int m = 1; m <= 6; ++m) {
        float qr = Hr[0], qi2 = Hi[0];
        #pragma unroll
        for (int i = 0; i < 3; ++i) {
            const int j = 2 * (i + 1);
            const float c = C14[(j * m) % 14], s2 = S14[(j * m) % 14];
            qr  = fmaf(qsr[i], c, qr);  qr  = fmaf(qdi[i], -s2, qr);
            qi2 = fmaf(qsi[i], c, qi2); qi2 = fmaf(qdr[i],  s2, qi2);
        }
        Qr[m] = qr; Qi[m] = qi2;
        float rr = (m & 1) ? -Hr[7] : Hr[7];
        float ri2 = (m & 1) ? -Hi[7] : Hi[7];
        #pragma unroll
        for (int i = 0; i < 3; ++i) {
            const int j = 2 * i + 1;
            const float c = C14[(j * m) % 14], s2 = S14[(j * m) % 14];
            rr  = fmaf(rsr[i], c, rr);  rr  = fmaf(rdi[i], -s2, rr);
            ri2 = fmaf(rsi[i], c, ri2); ri2 = fmaf(rdr[i],  s2, ri2);
        }
        Rr[m] = rr; Ri[m] = ri2;
    }

    __syncthreads();                    // bar2: all G reads done (convergent: placed
                                        // right after the long B/H/C compute)

    // ---------------- P transpose (packed bf16, single round) ----------------
    #pragma unroll
    for (int m = 0; m < 7; ++m) {
        T[(m * 8 + wv) * 64 + ln]       = pk_bf16(Qr[m] + Rr[m], Qi[m] + Ri[m]);
        T[((m + 7) * 8 + wv) * 64 + ln] = pk_bf16(Qr[m] - Rr[m], Qi[m] - Ri[m]);
    }
    __syncthreads();                    // bar3: P visible

    // ---------------- phase D: inverse rfft along w, non-temporal stores ----------------
    float* ob = out + (size_t)b * 196 * 768 + c0 + ln;
    #pragma unroll
    for (int rr = 0; rr < 2; ++rr) {
        const int row = rr ? r1 : r0;
        if (rr == 0 || two) {
            float a0[8], b0v[7];
            #pragma unroll
            for (int v = 0; v < 8; ++v) {
                float2 t = up_bf16(T[(row * 8 + v) * 64 + ln]);
                a0[v] = t.x * ((v == 0 || v == 7) ? (1.0f / 196.0f) : (2.0f / 196.0f));
                if (v >= 1 && v <= 6) b0v[v] = t.y * (2.0f / 196.0f);
            }
            const float o0 = a0[0] + a0[7] + a0[1] + a0[2] + a0[3] + a0[4] + a0[5] + a0[6];
            const float o7 = a0[0] - a0[7] - a0[1] + a0[2] - a0[3] + a0[4] - a0[5] + a0[6];
            __builtin_nontemporal_store(o0, &ob[(size_t)(row * 14 + 0) * 768]);
            __builtin_nontemporal_store(o7, &ob[(size_t)(row * 14 + 7) * 768]);
            #pragma unroll
            for (int wp = 1; wp <= 6; ++wp) {
                float t1 = (wp & 1) ? (a0[0] - a0[7]) : (a0[0] + a0[7]);
                float t2 = 0.f;
                #pragma unroll
                for (int v = 1; v <= 6; ++v) {
                    t1 = fmaf(a0[v],  C14[(v * wp) % 14], t1);
                    t2 = fmaf(b0v[v], S14[(v * wp) % 14], t2);
                }
                __builtin_nontemporal_store(t1 - t2, &ob[(size_t)(row * 14 + wp) * 768]);
                __builtin_nontemporal_store(t1 + t2, &ob[(size_t)(row * 14 + 14 - wp) * 768]);
            }
        }
    }
}

extern "C" void kernel_launch(void* const* d_in, const int* in_sizes, int n_in,
                              void* d_out, int out_size, void* d_ws, size_t ws_size,
                              hipStream_t stream) {
    const float* x   = (const float*)d_in[0];
    const float* wgt = (const float*)d_in[1];
    float*       o   = (float*)d_out;

    const int B = in_sizes[0] / (196 * 768);   // 256
    dim3 grid(B * CTILES), block(NT);
    gfnet_filter<<<grid, block, 0, stream>>>(x, wgt, o);
}